// Round 7
// baseline (944.735 us; speedup 1.0000x reference)
//
#include <hip/hip_runtime.h>
#include <hip/hip_bf16.h>

#define NA 100000
#define KN 6

typedef __attribute__((ext_vector_type(4))) float f32x4;
typedef __attribute__((ext_vector_type(8))) __bf16 bf16x8;
typedef __attribute__((ext_vector_type(8))) short s16x8;

__device__ inline unsigned short f2u(float f){
    __hip_bfloat16 h = __float2bfloat16(f);
    return *reinterpret_cast<unsigned short*>(&h);
}

// ---------------------------------------------------------------------------
// Pack all weight matrices [K x 256] (f32) into bf16 MFMA B-fragment order.
// (verbatim round-0)
// ---------------------------------------------------------------------------
__global__ __launch_bounds__(256) void pack_weights(
    const float* __restrict__ wi, const float* __restrict__ wh0,
    const float* __restrict__ wh1, const float* __restrict__ wah0,
    const float* __restrict__ wah, const float* __restrict__ wo,
    unsigned short* __restrict__ dst)
{
    int gid = blockIdx.x * 256 + threadIdx.x;
    if (gid >= 95232) return;
    const int starts[12] = {0,5120,14336,23552,32768,40960,49152,57344,62464,70656,78848,95232};
    int seg = 0;
    while (gid >= starts[seg+1]) seg++;
    int u = gid - starts[seg];
    const float* src; int K;
    if (seg == 0)      { src = wi;                        K = 133; }
    else if (seg < 4)  { src = wh0 + (seg-1)*69120;       K = 270; }
    else if (seg < 7)  { src = wh1 + (seg-4)*65536;       K = 256; }
    else if (seg == 7) { src = wah0;                      K = 133; }
    else if (seg < 10) { src = wah + (seg-8)*65536;       K = 256; }
    else               { src = wo;                        K = 512; }
    int l16 = u & 15, quad = (u >> 4) & 3, cbg = (u >> 6) & 15, kc = u >> 10;
    int col = cbg * 16 + l16;
    s16x8 v;
    #pragma unroll
    for (int j = 0; j < 8; j++){
        int k = kc * 32 + quad * 8 + j;
        ((unsigned short*)&v)[j] = (k < K) ? f2u(src[(size_t)k * 256 + col]) : (unsigned short)0;
    }
    *(s16x8*)(void*)(dst + (size_t)gid * 8) = v;
}

// ---------------------------------------------------------------------------
// bond_sum (verbatim round-0)
// ---------------------------------------------------------------------------
__global__ __launch_bounds__(256) void bond_gather(
    const float* __restrict__ f_bonds, const int* __restrict__ a2b,
    unsigned short* __restrict__ bsum)
{
    int t = blockIdx.x * 256 + threadIdx.x;
    int n = t >> 4, c = t & 15;
    if (n >= NA) return;
    float s = 0.f;
    if (c < 14){
        const int* rb = a2b + n * KN;
        #pragma unroll
        for (int k = 0; k < KN; k++) s += f_bonds[(size_t)rb[k] * 14 + c];
    }
    bsum[(size_t)n * 32 + c]      = (c < 14) ? f2u(s) : (unsigned short)0;
    bsum[(size_t)n * 32 + 16 + c] = 0;
}

// ---------------------------------------------------------------------------
// 64-row GEMM helpers (verbatim round-6)
// ---------------------------------------------------------------------------
template<int KC, int STRIDE>
__device__ inline void gemm_lds(const unsigned short* As, const unsigned short* __restrict__ Bp,
                                f32x4 (&acc)[4][4], int w, int quad, int l16)
{
    #pragma unroll
    for (int rb = 0; rb < 4; rb++)
        #pragma unroll
        for (int cb = 0; cb < 4; cb++)
            acc[rb][cb] = (f32x4){0.f, 0.f, 0.f, 0.f};
    #pragma unroll
    for (int kc = 0; kc < KC; kc++){
        bf16x8 afr[4], bfr[4];
        #pragma unroll
        for (int rb = 0; rb < 4; rb++)
            afr[rb] = *(const bf16x8*)(const void*)(As + (rb*16 + l16)*STRIDE + kc*32 + quad*8);
        #pragma unroll
        for (int cb = 0; cb < 4; cb++)
            bfr[cb] = *(const bf16x8*)(const void*)(Bp + ((((size_t)kc*16 + (w*4+cb))*4 + quad)*16 + l16)*8);
        #pragma unroll
        for (int rb = 0; rb < 4; rb++)
            #pragma unroll
            for (int cb = 0; cb < 4; cb++)
                acc[rb][cb] = __builtin_amdgcn_mfma_f32_16x16x32_bf16(afr[rb], bfr[cb], acc[rb][cb], 0, 0, 0);
    }
}

__device__ inline void add_bias(f32x4 (&acc)[4][4], const float* __restrict__ bias, int w, int l16)
{
    #pragma unroll
    for (int cb = 0; cb < 4; cb++){
        float b = bias[w*64 + cb*16 + l16];
        #pragma unroll
        for (int rb = 0; rb < 4; rb++)
            #pragma unroll
            for (int r = 0; r < 4; r++)
                acc[rb][cb][r] += b;
    }
}

// Butterfly partial sums into red[w][row*2(+1)] — NO barrier inside.
__device__ inline void wave_stats(const f32x4 (&acc)[4][4], float (*red)[128],
                                  int w, int quad, int l16)
{
    #pragma unroll
    for (int rb = 0; rb < 4; rb++){
        #pragma unroll
        for (int r = 0; r < 4; r++){
            float a0 = acc[rb][0][r], a1 = acc[rb][1][r], a2 = acc[rb][2][r], a3 = acc[rb][3][r];
            float s = a0 + a1 + a2 + a3;
            float q = a0*a0 + a1*a1 + a2*a2 + a3*a3;
            #pragma unroll
            for (int m = 1; m < 16; m <<= 1){
                s += __shfl_xor(s, m, 64);
                q += __shfl_xor(q, m, 64);
            }
            if (l16 == 0){
                int row = rb*16 + quad*4 + r;
                red[w][row*2]   = s;
                red[w][row*2+1] = q;
            }
        }
    }
}

// LN+PReLU; mu/rs computed inline from red (same summation order as before).
template<int STRIDE>
__device__ inline void ln_apply_lds(const f32x4 (&acc)[4][4], const float (*red)[128],
    const float* __restrict__ g, const float* __restrict__ bt, float al,
    unsigned short* As, int w, int quad, int l16)
{
    float gf[4], btf[4];
    #pragma unroll
    for (int cb = 0; cb < 4; cb++){
        int c = w*64 + cb*16 + l16;
        gf[cb] = g[c]; btf[cb] = bt[c];
    }
    #pragma unroll
    for (int rb = 0; rb < 4; rb++)
        #pragma unroll
        for (int r = 0; r < 4; r++){
            int row = rb*16 + quad*4 + r;
            float S1 = red[0][row*2]   + red[1][row*2]   + red[2][row*2]   + red[3][row*2];
            float S2 = red[0][row*2+1] + red[1][row*2+1] + red[2][row*2+1] + red[3][row*2+1];
            float mu  = S1 * (1.0f/256.0f);
            float var = S2 * (1.0f/256.0f) - mu*mu;
            float rs  = rsqrtf(var + 1e-5f);
            #pragma unroll
            for (int cb = 0; cb < 4; cb++){
                float y = (acc[rb][cb][r] - mu) * rs * gf[cb] + btf[cb];
                y = (y >= 0.f) ? y : al * y;
                As[row*STRIDE + w*64 + cb*16 + l16] = f2u(y);
            }
        }
}

// ---------------------------------------------------------------------------
// 32-row helpers (depth_step; verbatim round-6)
// ---------------------------------------------------------------------------
template<int KC, int STRIDE>
__device__ inline void gemm_lds32(const unsigned short* As, const unsigned short* __restrict__ Bp,
                                  f32x4 (&acc)[2][4], int w, int quad, int l16)
{
    #pragma unroll
    for (int rb = 0; rb < 2; rb++)
        #pragma unroll
        for (int cb = 0; cb < 4; cb++)
            acc[rb][cb] = (f32x4){0.f, 0.f, 0.f, 0.f};
    #pragma unroll
    for (int kc = 0; kc < KC; kc++){
        bf16x8 afr[2], bfr[4];
        #pragma unroll
        for (int rb = 0; rb < 2; rb++)
            afr[rb] = *(const bf16x8*)(const void*)(As + (rb*16 + l16)*STRIDE + kc*32 + quad*8);
        #pragma unroll
        for (int cb = 0; cb < 4; cb++)
            bfr[cb] = *(const bf16x8*)(const void*)(Bp + ((((size_t)kc*16 + (w*4+cb))*4 + quad)*16 + l16)*8);
        #pragma unroll
        for (int rb = 0; rb < 2; rb++)
            #pragma unroll
            for (int cb = 0; cb < 4; cb++)
                acc[rb][cb] = __builtin_amdgcn_mfma_f32_16x16x32_bf16(afr[rb], bfr[cb], acc[rb][cb], 0, 0, 0);
    }
}

__device__ inline void add_bias32(f32x4 (&acc)[2][4], const float* __restrict__ bias, int w, int l16)
{
    #pragma unroll
    for (int cb = 0; cb < 4; cb++){
        float b = bias[w*64 + cb*16 + l16];
        #pragma unroll
        for (int rb = 0; rb < 2; rb++)
            #pragma unroll
            for (int r = 0; r < 4; r++)
                acc[rb][cb][r] += b;
    }
}

__device__ inline void wave_stats32(const f32x4 (&acc)[2][4], float (*red)[64],
                                    int w, int quad, int l16)
{
    #pragma unroll
    for (int rb = 0; rb < 2; rb++){
        #pragma unroll
        for (int r = 0; r < 4; r++){
            float a0 = acc[rb][0][r], a1 = acc[rb][1][r], a2 = acc[rb][2][r], a3 = acc[rb][3][r];
            float s = a0 + a1 + a2 + a3;
            float q = a0*a0 + a1*a1 + a2*a2 + a3*a3;
            #pragma unroll
            for (int m = 1; m < 16; m <<= 1){
                s += __shfl_xor(s, m, 64);
                q += __shfl_xor(q, m, 64);
            }
            if (l16 == 0){
                int row = rb*16 + quad*4 + r;
                red[w][row*2]   = s;
                red[w][row*2+1] = q;
            }
        }
    }
}

template<int STRIDE>
__device__ inline void ln_apply_lds32(const f32x4 (&acc)[2][4], const float (*red)[64],
    const float* __restrict__ g, const float* __restrict__ bt, float al,
    unsigned short* As, int w, int quad, int l16)
{
    float gf[4], btf[4];
    #pragma unroll
    for (int cb = 0; cb < 4; cb++){
        int c = w*64 + cb*16 + l16;
        gf[cb] = g[c]; btf[cb] = bt[c];
    }
    #pragma unroll
    for (int rb = 0; rb < 2; rb++)
        #pragma unroll
        for (int r = 0; r < 4; r++){
            int row = rb*16 + quad*4 + r;
            float S1 = red[0][row*2]   + red[1][row*2]   + red[2][row*2]   + red[3][row*2];
            float S2 = red[0][row*2+1] + red[1][row*2+1] + red[2][row*2+1] + red[3][row*2+1];
            float mu  = S1 * (1.0f/256.0f);
            float var = S2 * (1.0f/256.0f) - mu*mu;
            float rs  = rsqrtf(var + 1e-5f);
            #pragma unroll
            for (int cb = 0; cb < 4; cb++){
                float y = (acc[rb][cb][r] - mu) * rs * gf[cb] + btf[cb];
                y = (y >= 0.f) ? y : al * y;
                As[row*STRIDE + w*64 + cb*16 + l16] = f2u(y);
            }
        }
}

// ---------------------------------------------------------------------------
// init: msg = (f_atoms @ wi + b), row0 = 0 (verbatim round-0, 64-row tile)
// ---------------------------------------------------------------------------
__global__ __launch_bounds__(256) void init_gemm(
    const float* __restrict__ fa, const unsigned short* __restrict__ Bp,
    const float* __restrict__ bias, float* __restrict__ msgf,
    unsigned short* __restrict__ msgb)
{
    __shared__ __align__(16) unsigned short As[64 * 168];
    const int tid = threadIdx.x, w = tid>>6, l = tid&63, quad = l>>4, l16 = l&15;
    const long rowbase = (long)blockIdx.x * 64;
    const int sr = tid >> 2, sk = (tid & 3) * 8;
    const long ns = rowbase + sr;
    #pragma unroll
    for (int kc = 0; kc < 5; kc++){
        bf16x8 v;
        #pragma unroll
        for (int j = 0; j < 8; j++){
            int k = kc*32 + sk + j;
            float x = (ns < NA && k < 133) ? fa[ns*133 + k] : 0.f;
            v[j] = (__bf16)x;
        }
        *(bf16x8*)(void*)(As + sr*168 + kc*32 + sk) = v;
    }
    __syncthreads();
    f32x4 acc[4][4];
    gemm_lds<5,168>(As, Bp, acc, w, quad, l16);
    float bb[4];
    #pragma unroll
    for (int cb = 0; cb < 4; cb++) bb[cb] = bias[w*64 + cb*16 + l16];
    #pragma unroll
    for (int rb = 0; rb < 4; rb++)
        #pragma unroll
        for (int r = 0; r < 4; r++){
            int row = rb*16 + quad*4 + r;
            long grow = rowbase + row;
            if (grow < NA){
                #pragma unroll
                for (int cb = 0; cb < 4; cb++){
                    int c = w*64 + cb*16 + l16;
                    float y = acc[rb][cb][r] + bb[cb];
                    if (grow == 0) y = 0.f;
                    msgf[grow*256 + c] = y;
                    msgb[grow*256 + c] = f2u(y);
                }
            }
        }
}

// ---------------------------------------------------------------------------
// One fused depth iteration — 32-row tile. Round-7 change: the msgf residual
// read (32 f32/thread, independent of all LDS/barrier state — this block's
// msgf rows are only written at kernel end, by this block) is HOISTED to
// just before the first barrier, where the gather registers die. Its HBM
// latency then overlaps GEMM1+LN+GEMM2 instead of sitting exposed after
// GEMM2. Numerics bit-identical (same addresses, same adds at the end).
// ---------------------------------------------------------------------------
__global__ __launch_bounds__(256) void depth_step(
    const unsigned short* __restrict__ msgb_in, const unsigned short* __restrict__ bsum,
    const int* __restrict__ a2a,
    const unsigned short* __restrict__ Bp1, const float* __restrict__ b1,
    const float* __restrict__ g1, const float* __restrict__ bt1, const float* __restrict__ a1,
    const unsigned short* __restrict__ Bp2, const float* __restrict__ b2,
    float* __restrict__ msgf, unsigned short* __restrict__ msgb_out,
    const int save_f)
{
    __shared__ __align__(16) unsigned short As[32 * 296];
    __shared__ float red[4][64];
    const int tid = threadIdx.x, w = tid>>6, l = tid&63, quad = l>>4, l16 = l&15;
    const int h = tid >> 5, lane32 = tid & 31;
    const long rowbase = (long)blockIdx.x * 32;

    // bsum staging prologue: As cols 256..287 for all 32 rows
    if (tid < 128){
        int r = tid >> 2, ch = tid & 3;
        long n = rowbase + r;
        bf16x8 bv = *(const bf16x8*)(const void*)(bsum + (size_t)n*32 + ch*8);
        *(bf16x8*)(void*)(As + r*296 + 256 + ch*8) = bv;
    }

    // prefetch all gather indices for this half-wave's 4 rows
    int idx[4][KN];
    #pragma unroll
    for (int i = 0; i < 4; i++){
        long n = rowbase + i*8 + h;
        const int* ra = a2a + n*KN;
        #pragma unroll
        for (int k = 0; k < KN; k++) idx[i][k] = ra[k];
    }

    // gather phase: half-wave per row, 4 rows each
    #pragma unroll
    for (int i = 0; i < 4; i++){
        int r = i*8 + h;
        float s[8] = {0.f,0.f,0.f,0.f,0.f,0.f,0.f,0.f};
        #pragma unroll
        for (int k = 0; k < KN; k++){
            bf16x8 v = *(const bf16x8*)(const void*)(msgb_in + (size_t)idx[i][k]*256 + lane32*8);
            #pragma unroll
            for (int j = 0; j < 8; j++) s[j] += (float)v[j];
        }
        bf16x8 o;
        #pragma unroll
        for (int j = 0; j < 8; j++) o[j] = (__bf16)s[j];
        *(bf16x8*)(void*)(As + r*296 + lane32*8) = o;
    }

    // ---- HOISTED residual load: overlaps GEMM1 + LN + GEMM2 ----
    // (all rows valid: NA % 32 == 0)
    float res[2][4][4];   // [rb][cb][r]
    #pragma unroll
    for (int rb = 0; rb < 2; rb++)
        #pragma unroll
        for (int r = 0; r < 4; r++){
            long grow = rowbase + rb*16 + quad*4 + r;
            #pragma unroll
            for (int cb = 0; cb < 4; cb++)
                res[rb][cb][r] = msgf[grow*256 + w*64 + cb*16 + l16];
        }
    __syncthreads();

    f32x4 acc[2][4];
    gemm_lds32<9,296>(As, Bp1, acc, w, quad, l16);
    add_bias32(acc, b1, w, l16);
    wave_stats32(acc, red, w, quad, l16);
    __syncthreads();
    ln_apply_lds32<296>(acc, red, g1, bt1, a1[0], As, w, quad, l16);
    __syncthreads();

    gemm_lds32<8,296>(As, Bp2, acc, w, quad, l16);
    float bb[4];
    #pragma unroll
    for (int cb = 0; cb < 4; cb++) bb[cb] = b2[w*64 + cb*16 + l16];
    #pragma unroll
    for (int rb = 0; rb < 2; rb++)
        #pragma unroll
        for (int r = 0; r < 4; r++){
            int row = rb*16 + quad*4 + r;
            long grow = rowbase + row;
            if (grow < NA){
                #pragma unroll
                for (int cb = 0; cb < 4; cb++){
                    int c = w*64 + cb*16 + l16;
                    float y = acc[rb][cb][r] + bb[cb] + res[rb][cb][r];
                    if (grow == 0) y = 0.f;
                    if (save_f) msgf[grow*256 + c] = y;
                    msgb_out[grow*256 + c] = f2u(y);
                }
            }
        }
}

// ---------------------------------------------------------------------------
// Fused tail (verbatim round-6: hoisted gather + idx prefetch + 1-barrier LN)
// ---------------------------------------------------------------------------
__global__ __launch_bounds__(256) void tail_kernel(
    const float* __restrict__ fa,
    const unsigned short* __restrict__ msgb, const int* __restrict__ a2a,
    const unsigned short* __restrict__ Wp,
    const float* __restrict__ wah0_b, const float* __restrict__ wah0_g,
    const float* __restrict__ wah0_bt, const float* __restrict__ wah0_a,
    const float* __restrict__ wah_b, const float* __restrict__ wah_g,
    const float* __restrict__ wah_bt, const float* __restrict__ wah_a,
    const float* __restrict__ tg, const float* __restrict__ tb, const float* __restrict__ ta,
    const float* __restrict__ wo_b, const float* __restrict__ wo_g,
    const float* __restrict__ wo_bt, const float* __restrict__ wo_a,
    float* __restrict__ out)
{
    __shared__ __align__(16) unsigned short As[64 * 520];
    __shared__ float red[4][128];
    const int tid = threadIdx.x, w = tid>>6, l = tid&63, quad = l>>4, l16 = l&15;
    const long rowbase = (long)blockIdx.x * 64;

    // ---- HOISTED: a_message gather + LN + PReLU -> cols 256..511 ----
    {
        const int h = tid >> 5, lane32 = tid & 31;
        const float talpha = ta[0];
        int idxA[8][KN];
        #pragma unroll
        for (int i = 0; i < 8; i++){
            long n = rowbase + i*8 + h;
            if (n < NA){
                const int* ra = a2a + n*KN;
                #pragma unroll
                for (int k = 0; k < KN; k++) idxA[i][k] = ra[k];
            } else {
                #pragma unroll
                for (int k = 0; k < KN; k++) idxA[i][k] = 0;
            }
        }
        #pragma unroll
        for (int i = 0; i < 8; i++){
            int r = i*8 + h;
            long n = rowbase + r;
            float s[8] = {0.f,0.f,0.f,0.f,0.f,0.f,0.f,0.f};
            if (n < NA){
                #pragma unroll
                for (int k = 0; k < KN; k++){
                    bf16x8 v = *(const bf16x8*)(const void*)(msgb + (size_t)idxA[i][k]*256 + lane32*8);
                    #pragma unroll
                    for (int j = 0; j < 8; j++) s[j] += (float)v[j];
                }
            }
            float p1 = 0.f, p2 = 0.f;
            #pragma unroll
            for (int j = 0; j < 8; j++){ p1 += s[j]; p2 += s[j]*s[j]; }
            #pragma unroll
            for (int m = 1; m < 32; m <<= 1){
                p1 += __shfl_xor(p1, m, 64);
                p2 += __shfl_xor(p2, m, 64);
            }
            float mu  = p1 * (1.0f/256.0f);
            float var = p2 * (1.0f/256.0f) - mu*mu;
            float rs  = rsqrtf(var + 1e-5f);
            bf16x8 o;
            #pragma unroll
            for (int j = 0; j < 8; j++){
                int c = lane32*8 + j;
                float y = (s[j] - mu) * rs * tg[c] + tb[c];
                y = (y >= 0.f) ? y : talpha * y;
                o[j] = (__bf16)y;
            }
            *(bf16x8*)(void*)(As + r*520 + 256 + lane32*8) = o;
        }
    }

    // stage f_atoms (K=133 -> 160, bf16) into cols 0..159
    {
        const int sr = tid >> 2, sk = (tid & 3) * 8;
        const long ns = rowbase + sr;
        #pragma unroll
        for (int kc = 0; kc < 5; kc++){
            bf16x8 v;
            #pragma unroll
            for (int j = 0; j < 8; j++){
                int k = kc*32 + sk + j;
                float x = (ns < NA && k < 133) ? fa[ns*133 + k] : 0.f;
                v[j] = (__bf16)x;
            }
            *(bf16x8*)(void*)(As + sr*520 + kc*32 + sk) = v;
        }
    }
    __syncthreads();

    f32x4 acc[4][4];
    // cc0 = PReLU(LN(f_atoms @ wah0 + b))
    gemm_lds<5,520>(As, Wp + 458752, acc, w, quad, l16);
    add_bias(acc, wah0_b, w, l16);
    wave_stats(acc, red, w, quad, l16);
    __syncthreads();
    ln_apply_lds<520>(acc, red, wah0_g, wah0_bt, wah0_a[0], As, w, quad, l16);
    __syncthreads();
    // cc1
    gemm_lds<8,520>(As, Wp + 499712, acc, w, quad, l16);
    add_bias(acc, wah_b, w, l16);
    wave_stats(acc, red, w, quad, l16);
    __syncthreads();
    ln_apply_lds<520>(acc, red, wah_g, wah_bt, wah_a[0], As, w, quad, l16);
    __syncthreads();
    // cc2 -> cols 0..255
    gemm_lds<8,520>(As, Wp + 565248, acc, w, quad, l16);
    add_bias(acc, wah_b + 256, w, l16);
    wave_stats(acc, red, w, quad, l16);
    __syncthreads();
    ln_apply_lds<520>(acc, red, wah_g + 256, wah_bt + 256, wah_a[1], As, w, quad, l16);
    __syncthreads();

    // out = PReLU(LN(a_input @ wo + b))
    gemm_lds<16,520>(As, Wp + 630784, acc, w, quad, l16);
    add_bias(acc, wo_b, w, l16);
    wave_stats(acc, red, w, quad, l16);
    __syncthreads();
    {
        const float al = wo_a[0];
        float gf[4], btf[4];
        #pragma unroll
        for (int cb = 0; cb < 4; cb++){
            int c = w*64 + cb*16 + l16;
            gf[cb] = wo_g[c]; btf[cb] = wo_bt[c];
        }
        #pragma unroll
        for (int rb = 0; rb < 4; rb++)
            #pragma unroll
            for (int r = 0; r < 4; r++){
                int row = rb*16 + quad*4 + r;
                long grow = rowbase + row;
                if (grow < NA){
                    float S1 = red[0][row*2]   + red[1][row*2]   + red[2][row*2]   + red[3][row*2];
                    float S2 = red[0][row*2+1] + red[1][row*2+1] + red[2][row*2+1] + red[3][row*2+1];
                    float mu  = S1 * (1.0f/256.0f);
                    float var = S2 * (1.0f/256.0f) - mu*mu;
                    float rs  = rsqrtf(var + 1e-5f);
                    #pragma unroll
                    for (int cb = 0; cb < 4; cb++){
                        int c = w*64 + cb*16 + l16;
                        float y = (acc[rb][cb][r] - mu) * rs * gf[cb] + btf[cb];
                        y = (y >= 0.f) ? y : al * y;
                        out[grow*256 + c] = y;
                    }
                }
            }
    }
}

// ---------------------------------------------------------------------------
extern "C" void kernel_launch(void* const* d_in, const int* in_sizes, int n_in,
                              void* d_out, int out_size, void* d_ws, size_t ws_size,
                              hipStream_t stream)
{
    const float* f_atoms = (const float*)d_in[0];
    const float* f_bonds = (const float*)d_in[1];
    const float* wi_w    = (const float*)d_in[2];
    const float* wi_b    = (const float*)d_in[3];
    const float* wh0_w   = (const float*)d_in[4];
    const float* wh0_b   = (const float*)d_in[5];
    const float* wh_g    = (const float*)d_in[6];
    const float* wh_bt   = (const float*)d_in[7];
    const float* wh_a    = (const float*)d_in[8];
    const float* wh1_w   = (const float*)d_in[9];
    const float* wh1_b   = (const float*)d_in[10];
    const float* tune_g  = (const float*)d_in[11];
    const float* tune_b  = (const float*)d_in[12];
    const float* tune_a  = (const float*)d_in[13];
    const float* wah0_w  = (const float*)d_in[14];
    const float* wah0_b  = (const float*)d_in[15];
    const float* wah0_g  = (const float*)d_in[16];
    const float* wah0_bt = (const float*)d_in[17];
    const float* wah0_a  = (const float*)d_in[18];
    const float* wah_w   = (const float*)d_in[19];
    const float* wah_b   = (const float*)d_in[20];
    const float* wah_g   = (const float*)d_in[21];
    const float* wah_bt  = (const float*)d_in[22];
    const float* wah_a   = (const float*)d_in[23];
    const float* wo_w    = (const float*)d_in[24];
    const float* wo_b    = (const float*)d_in[25];
    const float* wo_g    = (const float*)d_in[26];
    const float* wo_bt   = (const float*)d_in[27];
    const float* wo_a    = (const float*)d_in[28];
    const int* a2a = (const int*)d_in[29];
    const int* a2b = (const int*)d_in[30];

    char* ws = (char*)d_ws;
    float*          msgf  = (float*)ws;                              // 102,400,000 B
    unsigned short* msgb0 = (unsigned short*)(ws + 102400000LL);     //  51,200,000 B
    unsigned short* msgb1 = (unsigned short*)(ws + 153600000LL);     //  51,200,000 B
    unsigned short* bsum  = (unsigned short*)(ws + 204800000LL);     //   6,400,000 B
    unsigned short* Wp    = (unsigned short*)(ws + 211200000LL);     //   1,523,712 B

    const int GB   = (NA + 63) / 64;   // 1563
    const int GB32 = (NA + 31) / 32;   // 3125
    dim3 b256(256);

    pack_weights<<<372, b256, 0, stream>>>(wi_w, wh0_w, wh1_w, wah0_w, wah_w, wo_w, Wp);
    bond_gather<<<(NA*16 + 255)/256, b256, 0, stream>>>(f_bonds, a2b, bsum);
    init_gemm<<<GB, b256, 0, stream>>>(f_atoms, Wp + 0, wi_b, msgf, msgb0);

    // depth loop: bf16 shadow ping-pongs; last step skips the dead msgf store
    depth_step<<<GB32, b256, 0, stream>>>(msgb0, bsum, a2a,
        Wp + 40960,            wh0_b,       wh_g,       wh_bt,       wh_a,
        Wp + 262144,           wh1_b,       msgf, msgb1, 1);
    depth_step<<<GB32, b256, 0, stream>>>(msgb1, bsum, a2a,
        Wp + 40960 + 73728,    wh0_b + 256, wh_g + 256, wh_bt + 256, wh_a + 1,
        Wp + 262144 + 65536,   wh1_b + 256, msgf, msgb0, 1);
    depth_step<<<GB32, b256, 0, stream>>>(msgb0, bsum, a2a,
        Wp + 40960 + 147456,   wh0_b + 512, wh_g + 512, wh_bt + 512, wh_a + 2,
        Wp + 262144 + 131072,  wh1_b + 512, msgf, msgb1, 0);

    tail_kernel<<<GB, b256, 0, stream>>>(f_atoms, msgb1, a2a, Wp,
        wah0_b, wah0_g, wah0_bt, wah0_a,
        wah_b, wah_g, wah_bt, wah_a,
        tune_g, tune_b, tune_a,
        wo_b, wo_g, wo_bt, wo_a,
        (float*)d_out);
}

// Round 8
// 909.767 us; speedup vs baseline: 1.0384x; 1.0384x over previous
//
#include <hip/hip_runtime.h>
#include <hip/hip_bf16.h>

#define NA 100000
#define KN 6

typedef __attribute__((ext_vector_type(4))) float f32x4;
typedef __attribute__((ext_vector_type(8))) __bf16 bf16x8;
typedef __attribute__((ext_vector_type(8))) short s16x8;

__device__ inline unsigned short f2u(float f){
    __hip_bfloat16 h = __float2bfloat16(f);
    return *reinterpret_cast<unsigned short*>(&h);
}

// ---------------------------------------------------------------------------
// Pack all weight matrices [K x 256] (f32) into bf16 MFMA B-fragment order.
// (verbatim round-0)
// ---------------------------------------------------------------------------
__global__ __launch_bounds__(256) void pack_weights(
    const float* __restrict__ wi, const float* __restrict__ wh0,
    const float* __restrict__ wh1, const float* __restrict__ wah0,
    const float* __restrict__ wah, const float* __restrict__ wo,
    unsigned short* __restrict__ dst)
{
    int gid = blockIdx.x * 256 + threadIdx.x;
    if (gid >= 95232) return;
    const int starts[12] = {0,5120,14336,23552,32768,40960,49152,57344,62464,70656,78848,95232};
    int seg = 0;
    while (gid >= starts[seg+1]) seg++;
    int u = gid - starts[seg];
    const float* src; int K;
    if (seg == 0)      { src = wi;                        K = 133; }
    else if (seg < 4)  { src = wh0 + (seg-1)*69120;       K = 270; }
    else if (seg < 7)  { src = wh1 + (seg-4)*65536;       K = 256; }
    else if (seg == 7) { src = wah0;                      K = 133; }
    else if (seg < 10) { src = wah + (seg-8)*65536;       K = 256; }
    else               { src = wo;                        K = 512; }
    int l16 = u & 15, quad = (u >> 4) & 3, cbg = (u >> 6) & 15, kc = u >> 10;
    int col = cbg * 16 + l16;
    s16x8 v;
    #pragma unroll
    for (int j = 0; j < 8; j++){
        int k = kc * 32 + quad * 8 + j;
        ((unsigned short*)&v)[j] = (k < K) ? f2u(src[(size_t)k * 256 + col]) : (unsigned short)0;
    }
    *(s16x8*)(void*)(dst + (size_t)gid * 8) = v;
}

// ---------------------------------------------------------------------------
// bond_sum (verbatim round-0)
// ---------------------------------------------------------------------------
__global__ __launch_bounds__(256) void bond_gather(
    const float* __restrict__ f_bonds, const int* __restrict__ a2b,
    unsigned short* __restrict__ bsum)
{
    int t = blockIdx.x * 256 + threadIdx.x;
    int n = t >> 4, c = t & 15;
    if (n >= NA) return;
    float s = 0.f;
    if (c < 14){
        const int* rb = a2b + n * KN;
        #pragma unroll
        for (int k = 0; k < KN; k++) s += f_bonds[(size_t)rb[k] * 14 + c];
    }
    bsum[(size_t)n * 32 + c]      = (c < 14) ? f2u(s) : (unsigned short)0;
    bsum[(size_t)n * 32 + 16 + c] = 0;
}

// ---------------------------------------------------------------------------
// 64-row GEMM helpers (verbatim round-6)
// ---------------------------------------------------------------------------
template<int KC, int STRIDE>
__device__ inline void gemm_lds(const unsigned short* As, const unsigned short* __restrict__ Bp,
                                f32x4 (&acc)[4][4], int w, int quad, int l16)
{
    #pragma unroll
    for (int rb = 0; rb < 4; rb++)
        #pragma unroll
        for (int cb = 0; cb < 4; cb++)
            acc[rb][cb] = (f32x4){0.f, 0.f, 0.f, 0.f};
    #pragma unroll
    for (int kc = 0; kc < KC; kc++){
        bf16x8 afr[4], bfr[4];
        #pragma unroll
        for (int rb = 0; rb < 4; rb++)
            afr[rb] = *(const bf16x8*)(const void*)(As + (rb*16 + l16)*STRIDE + kc*32 + quad*8);
        #pragma unroll
        for (int cb = 0; cb < 4; cb++)
            bfr[cb] = *(const bf16x8*)(const void*)(Bp + ((((size_t)kc*16 + (w*4+cb))*4 + quad)*16 + l16)*8);
        #pragma unroll
        for (int rb = 0; rb < 4; rb++)
            #pragma unroll
            for (int cb = 0; cb < 4; cb++)
                acc[rb][cb] = __builtin_amdgcn_mfma_f32_16x16x32_bf16(afr[rb], bfr[cb], acc[rb][cb], 0, 0, 0);
    }
}

__device__ inline void add_bias(f32x4 (&acc)[4][4], const float* __restrict__ bias, int w, int l16)
{
    #pragma unroll
    for (int cb = 0; cb < 4; cb++){
        float b = bias[w*64 + cb*16 + l16];
        #pragma unroll
        for (int rb = 0; rb < 4; rb++)
            #pragma unroll
            for (int r = 0; r < 4; r++)
                acc[rb][cb][r] += b;
    }
}

// Butterfly partial sums into red[w][row*2(+1)] — NO barrier inside.
__device__ inline void wave_stats(const f32x4 (&acc)[4][4], float (*red)[128],
                                  int w, int quad, int l16)
{
    #pragma unroll
    for (int rb = 0; rb < 4; rb++){
        #pragma unroll
        for (int r = 0; r < 4; r++){
            float a0 = acc[rb][0][r], a1 = acc[rb][1][r], a2 = acc[rb][2][r], a3 = acc[rb][3][r];
            float s = a0 + a1 + a2 + a3;
            float q = a0*a0 + a1*a1 + a2*a2 + a3*a3;
            #pragma unroll
            for (int m = 1; m < 16; m <<= 1){
                s += __shfl_xor(s, m, 64);
                q += __shfl_xor(q, m, 64);
            }
            if (l16 == 0){
                int row = rb*16 + quad*4 + r;
                red[w][row*2]   = s;
                red[w][row*2+1] = q;
            }
        }
    }
}

// LN+PReLU; mu/rs computed inline from red (same summation order as before).
template<int STRIDE>
__device__ inline void ln_apply_lds(const f32x4 (&acc)[4][4], const float (*red)[128],
    const float* __restrict__ g, const float* __restrict__ bt, float al,
    unsigned short* As, int w, int quad, int l16)
{
    float gf[4], btf[4];
    #pragma unroll
    for (int cb = 0; cb < 4; cb++){
        int c = w*64 + cb*16 + l16;
        gf[cb] = g[c]; btf[cb] = bt[c];
    }
    #pragma unroll
    for (int rb = 0; rb < 4; rb++)
        #pragma unroll
        for (int r = 0; r < 4; r++){
            int row = rb*16 + quad*4 + r;
            float S1 = red[0][row*2]   + red[1][row*2]   + red[2][row*2]   + red[3][row*2];
            float S2 = red[0][row*2+1] + red[1][row*2+1] + red[2][row*2+1] + red[3][row*2+1];
            float mu  = S1 * (1.0f/256.0f);
            float var = S2 * (1.0f/256.0f) - mu*mu;
            float rs  = rsqrtf(var + 1e-5f);
            #pragma unroll
            for (int cb = 0; cb < 4; cb++){
                float y = (acc[rb][cb][r] - mu) * rs * gf[cb] + btf[cb];
                y = (y >= 0.f) ? y : al * y;
                As[row*STRIDE + w*64 + cb*16 + l16] = f2u(y);
            }
        }
}

// ---------------------------------------------------------------------------
// 32-row helpers (depth_step; verbatim round-6)
// ---------------------------------------------------------------------------
template<int KC, int STRIDE>
__device__ inline void gemm_lds32(const unsigned short* As, const unsigned short* __restrict__ Bp,
                                  f32x4 (&acc)[2][4], int w, int quad, int l16)
{
    #pragma unroll
    for (int rb = 0; rb < 2; rb++)
        #pragma unroll
        for (int cb = 0; cb < 4; cb++)
            acc[rb][cb] = (f32x4){0.f, 0.f, 0.f, 0.f};
    #pragma unroll
    for (int kc = 0; kc < KC; kc++){
        bf16x8 afr[2], bfr[4];
        #pragma unroll
        for (int rb = 0; rb < 2; rb++)
            afr[rb] = *(const bf16x8*)(const void*)(As + (rb*16 + l16)*STRIDE + kc*32 + quad*8);
        #pragma unroll
        for (int cb = 0; cb < 4; cb++)
            bfr[cb] = *(const bf16x8*)(const void*)(Bp + ((((size_t)kc*16 + (w*4+cb))*4 + quad)*16 + l16)*8);
        #pragma unroll
        for (int rb = 0; rb < 2; rb++)
            #pragma unroll
            for (int cb = 0; cb < 4; cb++)
                acc[rb][cb] = __builtin_amdgcn_mfma_f32_16x16x32_bf16(afr[rb], bfr[cb], acc[rb][cb], 0, 0, 0);
    }
}

__device__ inline void add_bias32(f32x4 (&acc)[2][4], const float* __restrict__ bias, int w, int l16)
{
    #pragma unroll
    for (int cb = 0; cb < 4; cb++){
        float b = bias[w*64 + cb*16 + l16];
        #pragma unroll
        for (int rb = 0; rb < 2; rb++)
            #pragma unroll
            for (int r = 0; r < 4; r++)
                acc[rb][cb][r] += b;
    }
}

__device__ inline void wave_stats32(const f32x4 (&acc)[2][4], float (*red)[64],
                                    int w, int quad, int l16)
{
    #pragma unroll
    for (int rb = 0; rb < 2; rb++){
        #pragma unroll
        for (int r = 0; r < 4; r++){
            float a0 = acc[rb][0][r], a1 = acc[rb][1][r], a2 = acc[rb][2][r], a3 = acc[rb][3][r];
            float s = a0 + a1 + a2 + a3;
            float q = a0*a0 + a1*a1 + a2*a2 + a3*a3;
            #pragma unroll
            for (int m = 1; m < 16; m <<= 1){
                s += __shfl_xor(s, m, 64);
                q += __shfl_xor(q, m, 64);
            }
            if (l16 == 0){
                int row = rb*16 + quad*4 + r;
                red[w][row*2]   = s;
                red[w][row*2+1] = q;
            }
        }
    }
}

template<int STRIDE>
__device__ inline void ln_apply_lds32(const f32x4 (&acc)[2][4], const float (*red)[64],
    const float* __restrict__ g, const float* __restrict__ bt, float al,
    unsigned short* As, int w, int quad, int l16)
{
    float gf[4], btf[4];
    #pragma unroll
    for (int cb = 0; cb < 4; cb++){
        int c = w*64 + cb*16 + l16;
        gf[cb] = g[c]; btf[cb] = bt[c];
    }
    #pragma unroll
    for (int rb = 0; rb < 2; rb++)
        #pragma unroll
        for (int r = 0; r < 4; r++){
            int row = rb*16 + quad*4 + r;
            float S1 = red[0][row*2]   + red[1][row*2]   + red[2][row*2]   + red[3][row*2];
            float S2 = red[0][row*2+1] + red[1][row*2+1] + red[2][row*2+1] + red[3][row*2+1];
            float mu  = S1 * (1.0f/256.0f);
            float var = S2 * (1.0f/256.0f) - mu*mu;
            float rs  = rsqrtf(var + 1e-5f);
            #pragma unroll
            for (int cb = 0; cb < 4; cb++){
                float y = (acc[rb][cb][r] - mu) * rs * gf[cb] + btf[cb];
                y = (y >= 0.f) ? y : al * y;
                As[row*STRIDE + w*64 + cb*16 + l16] = f2u(y);
            }
        }
}

// ---------------------------------------------------------------------------
// init: msg = (f_atoms @ wi + b), row0 = 0 (verbatim round-0, 64-row tile)
// ---------------------------------------------------------------------------
__global__ __launch_bounds__(256) void init_gemm(
    const float* __restrict__ fa, const unsigned short* __restrict__ Bp,
    const float* __restrict__ bias, float* __restrict__ msgf,
    unsigned short* __restrict__ msgb)
{
    __shared__ __align__(16) unsigned short As[64 * 168];
    const int tid = threadIdx.x, w = tid>>6, l = tid&63, quad = l>>4, l16 = l&15;
    const long rowbase = (long)blockIdx.x * 64;
    const int sr = tid >> 2, sk = (tid & 3) * 8;
    const long ns = rowbase + sr;
    #pragma unroll
    for (int kc = 0; kc < 5; kc++){
        bf16x8 v;
        #pragma unroll
        for (int j = 0; j < 8; j++){
            int k = kc*32 + sk + j;
            float x = (ns < NA && k < 133) ? fa[ns*133 + k] : 0.f;
            v[j] = (__bf16)x;
        }
        *(bf16x8*)(void*)(As + sr*168 + kc*32 + sk) = v;
    }
    __syncthreads();
    f32x4 acc[4][4];
    gemm_lds<5,168>(As, Bp, acc, w, quad, l16);
    float bb[4];
    #pragma unroll
    for (int cb = 0; cb < 4; cb++) bb[cb] = bias[w*64 + cb*16 + l16];
    #pragma unroll
    for (int rb = 0; rb < 4; rb++)
        #pragma unroll
        for (int r = 0; r < 4; r++){
            int row = rb*16 + quad*4 + r;
            long grow = rowbase + row;
            if (grow < NA){
                #pragma unroll
                for (int cb = 0; cb < 4; cb++){
                    int c = w*64 + cb*16 + l16;
                    float y = acc[rb][cb][r] + bb[cb];
                    if (grow == 0) y = 0.f;
                    msgf[grow*256 + c] = y;
                    msgb[grow*256 + c] = f2u(y);
                }
            }
        }
}

// ---------------------------------------------------------------------------
// One fused depth iteration — 32-row tile. Round-8: residual msgf load is
// issued AFTER the first __syncthreads (R7 issued it before — the compiler's
// vmcnt(0) drain at the barrier killed the overlap and exposed the latency).
// Placed here, the loads float across GEMM1 (~72 MFMA + 36 L2 loads) and are
// drained at the wave_stats barrier — by which point they're long done.
// Numerics bit-identical to R6/R7.
// ---------------------------------------------------------------------------
__global__ __launch_bounds__(256) void depth_step(
    const unsigned short* __restrict__ msgb_in, const unsigned short* __restrict__ bsum,
    const int* __restrict__ a2a,
    const unsigned short* __restrict__ Bp1, const float* __restrict__ b1,
    const float* __restrict__ g1, const float* __restrict__ bt1, const float* __restrict__ a1,
    const unsigned short* __restrict__ Bp2, const float* __restrict__ b2,
    float* __restrict__ msgf, unsigned short* __restrict__ msgb_out,
    const int save_f)
{
    __shared__ __align__(16) unsigned short As[32 * 296];
    __shared__ float red[4][64];
    const int tid = threadIdx.x, w = tid>>6, l = tid&63, quad = l>>4, l16 = l&15;
    const int h = tid >> 5, lane32 = tid & 31;
    const long rowbase = (long)blockIdx.x * 32;

    // bsum staging prologue: As cols 256..287 for all 32 rows
    if (tid < 128){
        int r = tid >> 2, ch = tid & 3;
        long n = rowbase + r;
        bf16x8 bv = *(const bf16x8*)(const void*)(bsum + (size_t)n*32 + ch*8);
        *(bf16x8*)(void*)(As + r*296 + 256 + ch*8) = bv;
    }

    // prefetch all gather indices for this half-wave's 4 rows
    int idx[4][KN];
    #pragma unroll
    for (int i = 0; i < 4; i++){
        long n = rowbase + i*8 + h;
        const int* ra = a2a + n*KN;
        #pragma unroll
        for (int k = 0; k < KN; k++) idx[i][k] = ra[k];
    }

    // gather phase: half-wave per row, 4 rows each
    #pragma unroll
    for (int i = 0; i < 4; i++){
        int r = i*8 + h;
        float s[8] = {0.f,0.f,0.f,0.f,0.f,0.f,0.f,0.f};
        #pragma unroll
        for (int k = 0; k < KN; k++){
            bf16x8 v = *(const bf16x8*)(const void*)(msgb_in + (size_t)idx[i][k]*256 + lane32*8);
            #pragma unroll
            for (int j = 0; j < 8; j++) s[j] += (float)v[j];
        }
        bf16x8 o;
        #pragma unroll
        for (int j = 0; j < 8; j++) o[j] = (__bf16)s[j];
        *(bf16x8*)(void*)(As + r*296 + lane32*8) = o;
    }
    __syncthreads();

    // ---- residual load, issued AFTER the barrier: floats across GEMM1 ----
    // (all rows valid: NA % 32 == 0; this block's msgf rows are written only
    //  at kernel end by this same block -> no hazard)
    float res[2][4][4];   // [rb][cb][r]
    #pragma unroll
    for (int rb = 0; rb < 2; rb++)
        #pragma unroll
        for (int r = 0; r < 4; r++){
            long grow = rowbase + rb*16 + quad*4 + r;
            #pragma unroll
            for (int cb = 0; cb < 4; cb++)
                res[rb][cb][r] = msgf[grow*256 + w*64 + cb*16 + l16];
        }

    f32x4 acc[2][4];
    gemm_lds32<9,296>(As, Bp1, acc, w, quad, l16);
    add_bias32(acc, b1, w, l16);
    wave_stats32(acc, red, w, quad, l16);
    __syncthreads();
    ln_apply_lds32<296>(acc, red, g1, bt1, a1[0], As, w, quad, l16);
    __syncthreads();

    gemm_lds32<8,296>(As, Bp2, acc, w, quad, l16);
    float bb[4];
    #pragma unroll
    for (int cb = 0; cb < 4; cb++) bb[cb] = b2[w*64 + cb*16 + l16];
    #pragma unroll
    for (int rb = 0; rb < 2; rb++)
        #pragma unroll
        for (int r = 0; r < 4; r++){
            int row = rb*16 + quad*4 + r;
            long grow = rowbase + row;
            if (grow < NA){
                #pragma unroll
                for (int cb = 0; cb < 4; cb++){
                    int c = w*64 + cb*16 + l16;
                    float y = acc[rb][cb][r] + bb[cb] + res[rb][cb][r];
                    if (grow == 0) y = 0.f;
                    if (save_f) msgf[grow*256 + c] = y;
                    msgb_out[grow*256 + c] = f2u(y);
                }
            }
        }
}

// ---------------------------------------------------------------------------
// Fused tail (verbatim round-6: hoisted gather + idx prefetch + 1-barrier LN)
// ---------------------------------------------------------------------------
__global__ __launch_bounds__(256) void tail_kernel(
    const float* __restrict__ fa,
    const unsigned short* __restrict__ msgb, const int* __restrict__ a2a,
    const unsigned short* __restrict__ Wp,
    const float* __restrict__ wah0_b, const float* __restrict__ wah0_g,
    const float* __restrict__ wah0_bt, const float* __restrict__ wah0_a,
    const float* __restrict__ wah_b, const float* __restrict__ wah_g,
    const float* __restrict__ wah_bt, const float* __restrict__ wah_a,
    const float* __restrict__ tg, const float* __restrict__ tb, const float* __restrict__ ta,
    const float* __restrict__ wo_b, const float* __restrict__ wo_g,
    const float* __restrict__ wo_bt, const float* __restrict__ wo_a,
    float* __restrict__ out)
{
    __shared__ __align__(16) unsigned short As[64 * 520];
    __shared__ float red[4][128];
    const int tid = threadIdx.x, w = tid>>6, l = tid&63, quad = l>>4, l16 = l&15;
    const long rowbase = (long)blockIdx.x * 64;

    // ---- HOISTED: a_message gather + LN + PReLU -> cols 256..511 ----
    {
        const int h = tid >> 5, lane32 = tid & 31;
        const float talpha = ta[0];
        int idxA[8][KN];
        #pragma unroll
        for (int i = 0; i < 8; i++){
            long n = rowbase + i*8 + h;
            if (n < NA){
                const int* ra = a2a + n*KN;
                #pragma unroll
                for (int k = 0; k < KN; k++) idxA[i][k] = ra[k];
            } else {
                #pragma unroll
                for (int k = 0; k < KN; k++) idxA[i][k] = 0;
            }
        }
        #pragma unroll
        for (int i = 0; i < 8; i++){
            int r = i*8 + h;
            long n = rowbase + r;
            float s[8] = {0.f,0.f,0.f,0.f,0.f,0.f,0.f,0.f};
            if (n < NA){
                #pragma unroll
                for (int k = 0; k < KN; k++){
                    bf16x8 v = *(const bf16x8*)(const void*)(msgb + (size_t)idxA[i][k]*256 + lane32*8);
                    #pragma unroll
                    for (int j = 0; j < 8; j++) s[j] += (float)v[j];
                }
            }
            float p1 = 0.f, p2 = 0.f;
            #pragma unroll
            for (int j = 0; j < 8; j++){ p1 += s[j]; p2 += s[j]*s[j]; }
            #pragma unroll
            for (int m = 1; m < 32; m <<= 1){
                p1 += __shfl_xor(p1, m, 64);
                p2 += __shfl_xor(p2, m, 64);
            }
            float mu  = p1 * (1.0f/256.0f);
            float var = p2 * (1.0f/256.0f) - mu*mu;
            float rs  = rsqrtf(var + 1e-5f);
            bf16x8 o;
            #pragma unroll
            for (int j = 0; j < 8; j++){
                int c = lane32*8 + j;
                float y = (s[j] - mu) * rs * tg[c] + tb[c];
                y = (y >= 0.f) ? y : talpha * y;
                o[j] = (__bf16)y;
            }
            *(bf16x8*)(void*)(As + r*520 + 256 + lane32*8) = o;
        }
    }

    // stage f_atoms (K=133 -> 160, bf16) into cols 0..159
    {
        const int sr = tid >> 2, sk = (tid & 3) * 8;
        const long ns = rowbase + sr;
        #pragma unroll
        for (int kc = 0; kc < 5; kc++){
            bf16x8 v;
            #pragma unroll
            for (int j = 0; j < 8; j++){
                int k = kc*32 + sk + j;
                float x = (ns < NA && k < 133) ? fa[ns*133 + k] : 0.f;
                v[j] = (__bf16)x;
            }
            *(bf16x8*)(void*)(As + sr*520 + kc*32 + sk) = v;
        }
    }
    __syncthreads();

    f32x4 acc[4][4];
    // cc0 = PReLU(LN(f_atoms @ wah0 + b))
    gemm_lds<5,520>(As, Wp + 458752, acc, w, quad, l16);
    add_bias(acc, wah0_b, w, l16);
    wave_stats(acc, red, w, quad, l16);
    __syncthreads();
    ln_apply_lds<520>(acc, red, wah0_g, wah0_bt, wah0_a[0], As, w, quad, l16);
    __syncthreads();
    // cc1
    gemm_lds<8,520>(As, Wp + 499712, acc, w, quad, l16);
    add_bias(acc, wah_b, w, l16);
    wave_stats(acc, red, w, quad, l16);
    __syncthreads();
    ln_apply_lds<520>(acc, red, wah_g, wah_bt, wah_a[0], As, w, quad, l16);
    __syncthreads();
    // cc2 -> cols 0..255
    gemm_lds<8,520>(As, Wp + 565248, acc, w, quad, l16);
    add_bias(acc, wah_b + 256, w, l16);
    wave_stats(acc, red, w, quad, l16);
    __syncthreads();
    ln_apply_lds<520>(acc, red, wah_g + 256, wah_bt + 256, wah_a[1], As, w, quad, l16);
    __syncthreads();

    // out = PReLU(LN(a_input @ wo + b))
    gemm_lds<16,520>(As, Wp + 630784, acc, w, quad, l16);
    add_bias(acc, wo_b, w, l16);
    wave_stats(acc, red, w, quad, l16);
    __syncthreads();
    {
        const float al = wo_a[0];
        float gf[4], btf[4];
        #pragma unroll
        for (int cb = 0; cb < 4; cb++){
            int c = w*64 + cb*16 + l16;
            gf[cb] = wo_g[c]; btf[cb] = wo_bt[c];
        }
        #pragma unroll
        for (int rb = 0; rb < 4; rb++)
            #pragma unroll
            for (int r = 0; r < 4; r++){
                int row = rb*16 + quad*4 + r;
                long grow = rowbase + row;
                if (grow < NA){
                    float S1 = red[0][row*2]   + red[1][row*2]   + red[2][row*2]   + red[3][row*2];
                    float S2 = red[0][row*2+1] + red[1][row*2+1] + red[2][row*2+1] + red[3][row*2+1];
                    float mu  = S1 * (1.0f/256.0f);
                    float var = S2 * (1.0f/256.0f) - mu*mu;
                    float rs  = rsqrtf(var + 1e-5f);
                    #pragma unroll
                    for (int cb = 0; cb < 4; cb++){
                        int c = w*64 + cb*16 + l16;
                        float y = (acc[rb][cb][r] - mu) * rs * gf[cb] + btf[cb];
                        y = (y >= 0.f) ? y : al * y;
                        out[grow*256 + c] = y;
                    }
                }
            }
    }
}

// ---------------------------------------------------------------------------
extern "C" void kernel_launch(void* const* d_in, const int* in_sizes, int n_in,
                              void* d_out, int out_size, void* d_ws, size_t ws_size,
                              hipStream_t stream)
{
    const float* f_atoms = (const float*)d_in[0];
    const float* f_bonds = (const float*)d_in[1];
    const float* wi_w    = (const float*)d_in[2];
    const float* wi_b    = (const float*)d_in[3];
    const float* wh0_w   = (const float*)d_in[4];
    const float* wh0_b   = (const float*)d_in[5];
    const float* wh_g    = (const float*)d_in[6];
    const float* wh_bt   = (const float*)d_in[7];
    const float* wh_a    = (const float*)d_in[8];
    const float* wh1_w   = (const float*)d_in[9];
    const float* wh1_b   = (const float*)d_in[10];
    const float* tune_g  = (const float*)d_in[11];
    const float* tune_b  = (const float*)d_in[12];
    const float* tune_a  = (const float*)d_in[13];
    const float* wah0_w  = (const float*)d_in[14];
    const float* wah0_b  = (const float*)d_in[15];
    const float* wah0_g  = (const float*)d_in[16];
    const float* wah0_bt = (const float*)d_in[17];
    const float* wah0_a  = (const float*)d_in[18];
    const float* wah_w   = (const float*)d_in[19];
    const float* wah_b   = (const float*)d_in[20];
    const float* wah_g   = (const float*)d_in[21];
    const float* wah_bt  = (const float*)d_in[22];
    const float* wah_a   = (const float*)d_in[23];
    const float* wo_w    = (const float*)d_in[24];
    const float* wo_b    = (const float*)d_in[25];
    const float* wo_g    = (const float*)d_in[26];
    const float* wo_bt   = (const float*)d_in[27];
    const float* wo_a    = (const float*)d_in[28];
    const int* a2a = (const int*)d_in[29];
    const int* a2b = (const int*)d_in[30];

    char* ws = (char*)d_ws;
    float*          msgf  = (float*)ws;                              // 102,400,000 B
    unsigned short* msgb0 = (unsigned short*)(ws + 102400000LL);     //  51,200,000 B
    unsigned short* msgb1 = (unsigned short*)(ws + 153600000LL);     //  51,200,000 B
    unsigned short* bsum  = (unsigned short*)(ws + 204800000LL);     //   6,400,000 B
    unsigned short* Wp    = (unsigned short*)(ws + 211200000LL);     //   1,523,712 B

    const int GB   = (NA + 63) / 64;   // 1563
    const int GB32 = (NA + 31) / 32;   // 3125
    dim3 b256(256);

    pack_weights<<<372, b256, 0, stream>>>(wi_w, wh0_w, wh1_w, wah0_w, wah_w, wo_w, Wp);
    bond_gather<<<(NA*16 + 255)/256, b256, 0, stream>>>(f_bonds, a2b, bsum);
    init_gemm<<<GB, b256, 0, stream>>>(f_atoms, Wp + 0, wi_b, msgf, msgb0);

    // depth loop: bf16 shadow ping-pongs; last step skips the dead msgf store
    depth_step<<<GB32, b256, 0, stream>>>(msgb0, bsum, a2a,
        Wp + 40960,            wh0_b,       wh_g,       wh_bt,       wh_a,
        Wp + 262144,           wh1_b,       msgf, msgb1, 1);
    depth_step<<<GB32, b256, 0, stream>>>(msgb1, bsum, a2a,
        Wp + 40960 + 73728,    wh0_b + 256, wh_g + 256, wh_bt + 256, wh_a + 1,
        Wp + 262144 + 65536,   wh1_b + 256, msgf, msgb0, 1);
    depth_step<<<GB32, b256, 0, stream>>>(msgb0, bsum, a2a,
        Wp + 40960 + 147456,   wh0_b + 512, wh_g + 512, wh_bt + 512, wh_a + 2,
        Wp + 262144 + 131072,  wh1_b + 512, msgf, msgb1, 0);

    tail_kernel<<<GB, b256, 0, stream>>>(f_atoms, msgb1, a2a, Wp,
        wah0_b, wah0_g, wah0_bt, wah0_a,
        wah_b, wah_g, wah_bt, wah_a,
        tune_g, tune_b, tune_a,
        wo_b, wo_g, wo_bt, wo_a,
        (float*)d_out);
}

// Round 11
// 851.746 us; speedup vs baseline: 1.1092x; 1.0681x over previous
//
#include <hip/hip_runtime.h>
#include <hip/hip_bf16.h>

#define NA 100000
#define KN 6

typedef __attribute__((ext_vector_type(4))) float f32x4;
typedef __attribute__((ext_vector_type(8))) __bf16 bf16x8;
typedef __attribute__((ext_vector_type(8))) short s16x8;

__device__ inline unsigned short f2u(float f){
    __hip_bfloat16 h = __float2bfloat16(f);
    return *reinterpret_cast<unsigned short*>(&h);
}

__device__ inline float u2f(unsigned short u){
    unsigned int x = ((unsigned int)u) << 16;   // bf16 -> f32 is exact
    return *reinterpret_cast<float*>(&x);
}

// ---------------------------------------------------------------------------
// Pack all weight matrices [K x 256] (f32) into bf16 MFMA B-fragment order.
// (verbatim round-0)
// ---------------------------------------------------------------------------
__global__ __launch_bounds__(256) void pack_weights(
    const float* __restrict__ wi, const float* __restrict__ wh0,
    const float* __restrict__ wh1, const float* __restrict__ wah0,
    const float* __restrict__ wah, const float* __restrict__ wo,
    unsigned short* __restrict__ dst)
{
    int gid = blockIdx.x * 256 + threadIdx.x;
    if (gid >= 95232) return;
    const int starts[12] = {0,5120,14336,23552,32768,40960,49152,57344,62464,70656,78848,95232};
    int seg = 0;
    while (gid >= starts[seg+1]) seg++;
    int u = gid - starts[seg];
    const float* src; int K;
    if (seg == 0)      { src = wi;                        K = 133; }
    else if (seg < 4)  { src = wh0 + (seg-1)*69120;       K = 270; }
    else if (seg < 7)  { src = wh1 + (seg-4)*65536;       K = 256; }
    else if (seg == 7) { src = wah0;                      K = 133; }
    else if (seg < 10) { src = wah + (seg-8)*65536;       K = 256; }
    else               { src = wo;                        K = 512; }
    int l16 = u & 15, quad = (u >> 4) & 3, cbg = (u >> 6) & 15, kc = u >> 10;
    int col = cbg * 16 + l16;
    s16x8 v;
    #pragma unroll
    for (int j = 0; j < 8; j++){
        int k = kc * 32 + quad * 8 + j;
        ((unsigned short*)&v)[j] = (k < K) ? f2u(src[(size_t)k * 256 + col]) : (unsigned short)0;
    }
    *(s16x8*)(void*)(dst + (size_t)gid * 8) = v;
}

// ---------------------------------------------------------------------------
// bond_sum (verbatim round-0)
// ---------------------------------------------------------------------------
__global__ __launch_bounds__(256) void bond_gather(
    const float* __restrict__ f_bonds, const int* __restrict__ a2b,
    unsigned short* __restrict__ bsum)
{
    int t = blockIdx.x * 256 + threadIdx.x;
    int n = t >> 4, c = t & 15;
    if (n >= NA) return;
    float s = 0.f;
    if (c < 14){
        const int* rb = a2b + n * KN;
        #pragma unroll
        for (int k = 0; k < KN; k++) s += f_bonds[(size_t)rb[k] * 14 + c];
    }
    bsum[(size_t)n * 32 + c]      = (c < 14) ? f2u(s) : (unsigned short)0;
    bsum[(size_t)n * 32 + 16 + c] = 0;
}

// ---------------------------------------------------------------------------
// 64-row GEMM helpers (init_gemm + tail_kernel)
// ---------------------------------------------------------------------------
template<int KC, int STRIDE>
__device__ inline void gemm_lds(const unsigned short* As, const unsigned short* __restrict__ Bp,
                                f32x4 (&acc)[4][4], int w, int quad, int l16)
{
    #pragma unroll
    for (int rb = 0; rb < 4; rb++)
        #pragma unroll
        for (int cb = 0; cb < 4; cb++)
            acc[rb][cb] = (f32x4){0.f, 0.f, 0.f, 0.f};
    #pragma unroll
    for (int kc = 0; kc < KC; kc++){
        bf16x8 afr[4], bfr[4];
        #pragma unroll
        for (int rb = 0; rb < 4; rb++)
            afr[rb] = *(const bf16x8*)(const void*)(As + (rb*16 + l16)*STRIDE + kc*32 + quad*8);
        #pragma unroll
        for (int cb = 0; cb < 4; cb++)
            bfr[cb] = *(const bf16x8*)(const void*)(Bp + ((((size_t)kc*16 + (w*4+cb))*4 + quad)*16 + l16)*8);
        #pragma unroll
        for (int rb = 0; rb < 4; rb++)
            #pragma unroll
            for (int cb = 0; cb < 4; cb++)
                acc[rb][cb] = __builtin_amdgcn_mfma_f32_16x16x32_bf16(afr[rb], bfr[cb], acc[rb][cb], 0, 0, 0);
    }
}

__device__ inline void add_bias(f32x4 (&acc)[4][4], const float* __restrict__ bias, int w, int l16)
{
    #pragma unroll
    for (int cb = 0; cb < 4; cb++){
        float b = bias[w*64 + cb*16 + l16];
        #pragma unroll
        for (int rb = 0; rb < 4; rb++)
            #pragma unroll
            for (int r = 0; r < 4; r++)
                acc[rb][cb][r] += b;
    }
}

// Butterfly partial sums into red[w][row*2(+1)] — NO barrier inside.
__device__ inline void wave_stats(const f32x4 (&acc)[4][4], float (*red)[128],
                                  int w, int quad, int l16)
{
    #pragma unroll
    for (int rb = 0; rb < 4; rb++){
        #pragma unroll
        for (int r = 0; r < 4; r++){
            float a0 = acc[rb][0][r], a1 = acc[rb][1][r], a2 = acc[rb][2][r], a3 = acc[rb][3][r];
            float s = a0 + a1 + a2 + a3;
            float q = a0*a0 + a1*a1 + a2*a2 + a3*a3;
            #pragma unroll
            for (int m = 1; m < 16; m <<= 1){
                s += __shfl_xor(s, m, 64);
                q += __shfl_xor(q, m, 64);
            }
            if (l16 == 0){
                int row = rb*16 + quad*4 + r;
                red[w][row*2]   = s;
                red[w][row*2+1] = q;
            }
        }
    }
}

// LN+PReLU; mu/rs computed inline from red (same summation order as before).
template<int STRIDE>
__device__ inline void ln_apply_lds(const f32x4 (&acc)[4][4], const float (*red)[128],
    const float* __restrict__ g, const float* __restrict__ bt, float al,
    unsigned short* As, int w, int quad, int l16)
{
    float gf[4], btf[4];
    #pragma unroll
    for (int cb = 0; cb < 4; cb++){
        int c = w*64 + cb*16 + l16;
        gf[cb] = g[c]; btf[cb] = bt[c];
    }
    #pragma unroll
    for (int rb = 0; rb < 4; rb++)
        #pragma unroll
        for (int r = 0; r < 4; r++){
            int row = rb*16 + quad*4 + r;
            float S1 = red[0][row*2]   + red[1][row*2]   + red[2][row*2]   + red[3][row*2];
            float S2 = red[0][row*2+1] + red[1][row*2+1] + red[2][row*2+1] + red[3][row*2+1];
            float mu  = S1 * (1.0f/256.0f);
            float var = S2 * (1.0f/256.0f) - mu*mu;
            float rs  = rsqrtf(var + 1e-5f);
            #pragma unroll
            for (int cb = 0; cb < 4; cb++){
                float y = (acc[rb][cb][r] - mu) * rs * gf[cb] + btf[cb];
                y = (y >= 0.f) ? y : al * y;
                As[row*STRIDE + w*64 + cb*16 + l16] = f2u(y);
            }
        }
}

// ---------------------------------------------------------------------------
// 32-row helpers (depth_step; proven since R3/R6)
// ---------------------------------------------------------------------------
template<int KC, int STRIDE>
__device__ inline void gemm_lds32(const unsigned short* As, const unsigned short* __restrict__ Bp,
                                  f32x4 (&acc)[2][4], int w, int quad, int l16)
{
    #pragma unroll
    for (int rb = 0; rb < 2; rb++)
        #pragma unroll
        for (int cb = 0; cb < 4; cb++)
            acc[rb][cb] = (f32x4){0.f, 0.f, 0.f, 0.f};
    #pragma unroll
    for (int kc = 0; kc < KC; kc++){
        bf16x8 afr[2], bfr[4];
        #pragma unroll
        for (int rb = 0; rb < 2; rb++)
            afr[rb] = *(const bf16x8*)(const void*)(As + (rb*16 + l16)*STRIDE + kc*32 + quad*8);
        #pragma unroll
        for (int cb = 0; cb < 4; cb++)
            bfr[cb] = *(const bf16x8*)(const void*)(Bp + ((((size_t)kc*16 + (w*4+cb))*4 + quad)*16 + l16)*8);
        #pragma unroll
        for (int rb = 0; rb < 2; rb++)
            #pragma unroll
            for (int cb = 0; cb < 4; cb++)
                acc[rb][cb] = __builtin_amdgcn_mfma_f32_16x16x32_bf16(afr[rb], bfr[cb], acc[rb][cb], 0, 0, 0);
    }
}

__device__ inline void add_bias32(f32x4 (&acc)[2][4], const float* __restrict__ bias, int w, int l16)
{
    #pragma unroll
    for (int cb = 0; cb < 4; cb++){
        float b = bias[w*64 + cb*16 + l16];
        #pragma unroll
        for (int rb = 0; rb < 2; rb++)
            #pragma unroll
            for (int r = 0; r < 4; r++)
                acc[rb][cb][r] += b;
    }
}

__device__ inline void wave_stats32(const f32x4 (&acc)[2][4], float (*red)[64],
                                    int w, int quad, int l16)
{
    #pragma unroll
    for (int rb = 0; rb < 2; rb++){
        #pragma unroll
        for (int r = 0; r < 4; r++){
            float a0 = acc[rb][0][r], a1 = acc[rb][1][r], a2 = acc[rb][2][r], a3 = acc[rb][3][r];
            float s = a0 + a1 + a2 + a3;
            float q = a0*a0 + a1*a1 + a2*a2 + a3*a3;
            #pragma unroll
            for (int m = 1; m < 16; m <<= 1){
                s += __shfl_xor(s, m, 64);
                q += __shfl_xor(q, m, 64);
            }
            if (l16 == 0){
                int row = rb*16 + quad*4 + r;
                red[w][row*2]   = s;
                red[w][row*2+1] = q;
            }
        }
    }
}

template<int STRIDE>
__device__ inline void ln_apply_lds32(const f32x4 (&acc)[2][4], const float (*red)[64],
    const float* __restrict__ g, const float* __restrict__ bt, float al,
    unsigned short* As, int w, int quad, int l16)
{
    float gf[4], btf[4];
    #pragma unroll
    for (int cb = 0; cb < 4; cb++){
        int c = w*64 + cb*16 + l16;
        gf[cb] = g[c]; btf[cb] = bt[c];
    }
    #pragma unroll
    for (int rb = 0; rb < 2; rb++)
        #pragma unroll
        for (int r = 0; r < 4; r++){
            int row = rb*16 + quad*4 + r;
            float S1 = red[0][row*2]   + red[1][row*2]   + red[2][row*2]   + red[3][row*2];
            float S2 = red[0][row*2+1] + red[1][row*2+1] + red[2][row*2+1] + red[3][row*2+1];
            float mu  = S1 * (1.0f/256.0f);
            float var = S2 * (1.0f/256.0f) - mu*mu;
            float rs  = rsqrtf(var + 1e-5f);
            #pragma unroll
            for (int cb = 0; cb < 4; cb++){
                float y = (acc[rb][cb][r] - mu) * rs * gf[cb] + btf[cb];
                y = (y >= 0.f) ? y : al * y;
                As[row*STRIDE + w*64 + cb*16 + l16] = f2u(y);
            }
        }
}

// ---------------------------------------------------------------------------
// init: msg = (f_atoms @ wi + b), row0 = 0. bf16 state only — msgf (f32
// carry) eliminated; msgb IS the state. Saves 100 MB of stores.
// ---------------------------------------------------------------------------
__global__ __launch_bounds__(256) void init_gemm(
    const float* __restrict__ fa, const unsigned short* __restrict__ Bp,
    const float* __restrict__ bias, unsigned short* __restrict__ msgb)
{
    __shared__ __align__(16) unsigned short As[64 * 168];
    const int tid = threadIdx.x, w = tid>>6, l = tid&63, quad = l>>4, l16 = l&15;
    const long rowbase = (long)blockIdx.x * 64;
    const int sr = tid >> 2, sk = (tid & 3) * 8;
    const long ns = rowbase + sr;
    #pragma unroll
    for (int kc = 0; kc < 5; kc++){
        bf16x8 v;
        #pragma unroll
        for (int j = 0; j < 8; j++){
            int k = kc*32 + sk + j;
            float x = (ns < NA && k < 133) ? fa[ns*133 + k] : 0.f;
            v[j] = (__bf16)x;
        }
        *(bf16x8*)(void*)(As + sr*168 + kc*32 + sk) = v;
    }
    __syncthreads();
    f32x4 acc[4][4];
    gemm_lds<5,168>(As, Bp, acc, w, quad, l16);
    float bb[4];
    #pragma unroll
    for (int cb = 0; cb < 4; cb++) bb[cb] = bias[w*64 + cb*16 + l16];
    #pragma unroll
    for (int rb = 0; rb < 4; rb++)
        #pragma unroll
        for (int r = 0; r < 4; r++){
            int row = rb*16 + quad*4 + r;
            long grow = rowbase + row;
            if (grow < NA){
                #pragma unroll
                for (int cb = 0; cb < 4; cb++){
                    int c = w*64 + cb*16 + l16;
                    float y = acc[rb][cb][r] + bb[cb];
                    if (grow == 0) y = 0.f;
                    msgb[grow*256 + c] = f2u(y);
                }
            }
        }
}

// ---------------------------------------------------------------------------
// One fused depth iteration — 32-row tile. Residual carry is bf16 (read own
// row of msgb_in instead of msgf f32) — saves 150 MB/step of traffic. One
// extra bf16 rounding of the carry per step (bf16->f32 exact). Residual
// load keeps R8's proven placement: issued AFTER the first barrier, floats
// across GEMM1, consumed in the epilogue.
// ---------------------------------------------------------------------------
__global__ __launch_bounds__(256) void depth_step(
    const unsigned short* __restrict__ msgb_in, const unsigned short* __restrict__ bsum,
    const int* __restrict__ a2a,
    const unsigned short* __restrict__ Bp1, const float* __restrict__ b1,
    const float* __restrict__ g1, const float* __restrict__ bt1, const float* __restrict__ a1,
    const unsigned short* __restrict__ Bp2, const float* __restrict__ b2,
    unsigned short* __restrict__ msgb_out)
{
    __shared__ __align__(16) unsigned short As[32 * 296];
    __shared__ float red[4][64];
    const int tid = threadIdx.x, w = tid>>6, l = tid&63, quad = l>>4, l16 = l&15;
    const int h = tid >> 5, lane32 = tid & 31;
    const long rowbase = (long)blockIdx.x * 32;

    // bsum staging prologue: As cols 256..287 for all 32 rows
    if (tid < 128){
        int r = tid >> 2, ch = tid & 3;
        long n = rowbase + r;
        bf16x8 bv = *(const bf16x8*)(const void*)(bsum + (size_t)n*32 + ch*8);
        *(bf16x8*)(void*)(As + r*296 + 256 + ch*8) = bv;
    }

    // prefetch all gather indices for this half-wave's 4 rows
    int idx[4][KN];
    #pragma unroll
    for (int i = 0; i < 4; i++){
        long n = rowbase + i*8 + h;
        const int* ra = a2a + n*KN;
        #pragma unroll
        for (int k = 0; k < KN; k++) idx[i][k] = ra[k];
    }

    // gather phase: half-wave per row, 4 rows each
    #pragma unroll
    for (int i = 0; i < 4; i++){
        int r = i*8 + h;
        float s[8] = {0.f,0.f,0.f,0.f,0.f,0.f,0.f,0.f};
        #pragma unroll
        for (int k = 0; k < KN; k++){
            bf16x8 v = *(const bf16x8*)(const void*)(msgb_in + (size_t)idx[i][k]*256 + lane32*8);
            #pragma unroll
            for (int j = 0; j < 8; j++) s[j] += (float)v[j];
        }
        bf16x8 o;
        #pragma unroll
        for (int j = 0; j < 8; j++) o[j] = (__bf16)s[j];
        *(bf16x8*)(void*)(As + r*296 + lane32*8) = o;
    }
    __syncthreads();

    // residual load (bf16 state), issued AFTER the barrier: floats across GEMM1
    float res[2][4][4];   // [rb][cb][r]
    #pragma unroll
    for (int rb = 0; rb < 2; rb++)
        #pragma unroll
        for (int r = 0; r < 4; r++){
            long grow = rowbase + rb*16 + quad*4 + r;
            #pragma unroll
            for (int cb = 0; cb < 4; cb++)
                res[rb][cb][r] = u2f(msgb_in[grow*256 + w*64 + cb*16 + l16]);
        }

    f32x4 acc[2][4];
    gemm_lds32<9,296>(As, Bp1, acc, w, quad, l16);
    add_bias32(acc, b1, w, l16);
    wave_stats32(acc, red, w, quad, l16);
    __syncthreads();
    ln_apply_lds32<296>(acc, red, g1, bt1, a1[0], As, w, quad, l16);
    __syncthreads();

    gemm_lds32<8,296>(As, Bp2, acc, w, quad, l16);
    float bb[4];
    #pragma unroll
    for (int cb = 0; cb < 4; cb++) bb[cb] = b2[w*64 + cb*16 + l16];
    #pragma unroll
    for (int rb = 0; rb < 2; rb++)
        #pragma unroll
        for (int r = 0; r < 4; r++){
            int row = rb*16 + quad*4 + r;
            long grow = rowbase + row;
            if (grow < NA){
                #pragma unroll
                for (int cb = 0; cb < 4; cb++){
                    int c = w*64 + cb*16 + l16;
                    float y = acc[rb][cb][r] + bb[cb] + res[rb][cb][r];
                    if (grow == 0) y = 0.f;
                    msgb_out[grow*256 + c] = f2u(y);
                }
            }
        }
}

// ---------------------------------------------------------------------------
// Fused tail (verbatim round-8: 64-row tile, hoisted gather + idx prefetch +
// single-barrier LN). 32-row tail is RADIOACTIVE (failed R2 + R9) — do not
// re-attempt without new counter evidence.
// ---------------------------------------------------------------------------
__global__ __launch_bounds__(256) void tail_kernel(
    const float* __restrict__ fa,
    const unsigned short* __restrict__ msgb, const int* __restrict__ a2a,
    const unsigned short* __restrict__ Wp,
    const float* __restrict__ wah0_b, const float* __restrict__ wah0_g,
    const float* __restrict__ wah0_bt, const float* __restrict__ wah0_a,
    const float* __restrict__ wah_b, const float* __restrict__ wah_g,
    const float* __restrict__ wah_bt, const float* __restrict__ wah_a,
    const float* __restrict__ tg, const float* __restrict__ tb, const float* __restrict__ ta,
    const float* __restrict__ wo_b, const float* __restrict__ wo_g,
    const float* __restrict__ wo_bt, const float* __restrict__ wo_a,
    float* __restrict__ out)
{
    __shared__ __align__(16) unsigned short As[64 * 520];
    __shared__ float red[4][128];
    const int tid = threadIdx.x, w = tid>>6, l = tid&63, quad = l>>4, l16 = l&15;
    const long rowbase = (long)blockIdx.x * 64;

    // ---- HOISTED: a_message gather + LN + PReLU -> cols 256..511 ----
    {
        const int h = tid >> 5, lane32 = tid & 31;
        const float talpha = ta[0];
        int idxA[8][KN];
        #pragma unroll
        for (int i = 0; i < 8; i++){
            long n = rowbase + i*8 + h;
            if (n < NA){
                const int* ra = a2a + n*KN;
                #pragma unroll
                for (int k = 0; k < KN; k++) idxA[i][k] = ra[k];
            } else {
                #pragma unroll
                for (int k = 0; k < KN; k++) idxA[i][k] = 0;
            }
        }
        #pragma unroll
        for (int i = 0; i < 8; i++){
            int r = i*8 + h;
            long n = rowbase + r;
            float s[8] = {0.f,0.f,0.f,0.f,0.f,0.f,0.f,0.f};
            if (n < NA){
                #pragma unroll
                for (int k = 0; k < KN; k++){
                    bf16x8 v = *(const bf16x8*)(const void*)(msgb + (size_t)idxA[i][k]*256 + lane32*8);
                    #pragma unroll
                    for (int j = 0; j < 8; j++) s[j] += (float)v[j];
                }
            }
            float p1 = 0.f, p2 = 0.f;
            #pragma unroll
            for (int j = 0; j < 8; j++){ p1 += s[j]; p2 += s[j]*s[j]; }
            #pragma unroll
            for (int m = 1; m < 32; m <<= 1){
                p1 += __shfl_xor(p1, m, 64);
                p2 += __shfl_xor(p2, m, 64);
            }
            float mu  = p1 * (1.0f/256.0f);
            float var = p2 * (1.0f/256.0f) - mu*mu;
            float rs  = rsqrtf(var + 1e-5f);
            bf16x8 o;
            #pragma unroll
            for (int j = 0; j < 8; j++){
                int c = lane32*8 + j;
                float y = (s[j] - mu) * rs * tg[c] + tb[c];
                y = (y >= 0.f) ? y : talpha * y;
                o[j] = (__bf16)y;
            }
            *(bf16x8*)(void*)(As + r*520 + 256 + lane32*8) = o;
        }
    }

    // stage f_atoms (K=133 -> 160, bf16) into cols 0..159
    {
        const int sr = tid >> 2, sk = (tid & 3) * 8;
        const long ns = rowbase + sr;
        #pragma unroll
        for (int kc = 0; kc < 5; kc++){
            bf16x8 v;
            #pragma unroll
            for (int j = 0; j < 8; j++){
                int k = kc*32 + sk + j;
                float x = (ns < NA && k < 133) ? fa[ns*133 + k] : 0.f;
                v[j] = (__bf16)x;
            }
            *(bf16x8*)(void*)(As + sr*520 + kc*32 + sk) = v;
        }
    }
    __syncthreads();

    f32x4 acc[4][4];
    // cc0 = PReLU(LN(f_atoms @ wah0 + b))
    gemm_lds<5,520>(As, Wp + 458752, acc, w, quad, l16);
    add_bias(acc, wah0_b, w, l16);
    wave_stats(acc, red, w, quad, l16);
    __syncthreads();
    ln_apply_lds<520>(acc, red, wah0_g, wah0_bt, wah0_a[0], As, w, quad, l16);
    __syncthreads();
    // cc1
    gemm_lds<8,520>(As, Wp + 499712, acc, w, quad, l16);
    add_bias(acc, wah_b, w, l16);
    wave_stats(acc, red, w, quad, l16);
    __syncthreads();
    ln_apply_lds<520>(acc, red, wah_g, wah_bt, wah_a[0], As, w, quad, l16);
    __syncthreads();
    // cc2 -> cols 0..255
    gemm_lds<8,520>(As, Wp + 565248, acc, w, quad, l16);
    add_bias(acc, wah_b + 256, w, l16);
    wave_stats(acc, red, w, quad, l16);
    __syncthreads();
    ln_apply_lds<520>(acc, red, wah_g + 256, wah_bt + 256, wah_a[1], As, w, quad, l16);
    __syncthreads();

    // out = PReLU(LN(a_input @ wo + b))
    gemm_lds<16,520>(As, Wp + 630784, acc, w, quad, l16);
    add_bias(acc, wo_b, w, l16);
    wave_stats(acc, red, w, quad, l16);
    __syncthreads();
    {
        const float al = wo_a[0];
        float gf[4], btf[4];
        #pragma unroll
        for (int cb = 0; cb < 4; cb++){
            int c = w*64 + cb*16 + l16;
            gf[cb] = wo_g[c]; btf[cb] = wo_bt[c];
        }
        #pragma unroll
        for (int rb = 0; rb < 4; rb++)
            #pragma unroll
            for (int r = 0; r < 4; r++){
                int row = rb*16 + quad*4 + r;
                long grow = rowbase + row;
                if (grow < NA){
                    float S1 = red[0][row*2]   + red[1][row*2]   + red[2][row*2]   + red[3][row*2];
                    float S2 = red[0][row*2+1] + red[1][row*2+1] + red[2][row*2+1] + red[3][row*2+1];
                    float mu  = S1 * (1.0f/256.0f);
                    float var = S2 * (1.0f/256.0f) - mu*mu;
                    float rs  = rsqrtf(var + 1e-5f);
                    #pragma unroll
                    for (int cb = 0; cb < 4; cb++){
                        int c = w*64 + cb*16 + l16;
                        float y = (acc[rb][cb][r] - mu) * rs * gf[cb] + btf[cb];
                        y = (y >= 0.f) ? y : al * y;
                        out[grow*256 + c] = y;
                    }
                }
            }
    }
}

// ---------------------------------------------------------------------------
extern "C" void kernel_launch(void* const* d_in, const int* in_sizes, int n_in,
                              void* d_out, int out_size, void* d_ws, size_t ws_size,
                              hipStream_t stream)
{
    const float* f_atoms = (const float*)d_in[0];
    const float* f_bonds = (const float*)d_in[1];
    const float* wi_w    = (const float*)d_in[2];
    const float* wi_b    = (const float*)d_in[3];
    const float* wh0_w   = (const float*)d_in[4];
    const float* wh0_b   = (const float*)d_in[5];
    const float* wh_g    = (const float*)d_in[6];
    const float* wh_bt   = (const float*)d_in[7];
    const float* wh_a    = (const float*)d_in[8];
    const float* wh1_w   = (const float*)d_in[9];
    const float* wh1_b   = (const float*)d_in[10];
    const float* tune_g  = (const float*)d_in[11];
    const float* tune_b  = (const float*)d_in[12];
    const float* tune_a  = (const float*)d_in[13];
    const float* wah0_w  = (const float*)d_in[14];
    const float* wah0_b  = (const float*)d_in[15];
    const float* wah0_g  = (const float*)d_in[16];
    const float* wah0_bt = (const float*)d_in[17];
    const float* wah0_a  = (const float*)d_in[18];
    const float* wah_w   = (const float*)d_in[19];
    const float* wah_b   = (const float*)d_in[20];
    const float* wah_g   = (const float*)d_in[21];
    const float* wah_bt  = (const float*)d_in[22];
    const float* wah_a   = (const float*)d_in[23];
    const float* wo_w    = (const float*)d_in[24];
    const float* wo_b    = (const float*)d_in[25];
    const float* wo_g    = (const float*)d_in[26];
    const float* wo_bt   = (const float*)d_in[27];
    const float* wo_a    = (const float*)d_in[28];
    const int* a2a = (const int*)d_in[29];
    const int* a2b = (const int*)d_in[30];

    char* ws = (char*)d_ws;
    unsigned short* msgb0 = (unsigned short*)(ws + 102400000LL);     //  51,200,000 B
    unsigned short* msgb1 = (unsigned short*)(ws + 153600000LL);     //  51,200,000 B
    unsigned short* bsum  = (unsigned short*)(ws + 204800000LL);     //   6,400,000 B
    unsigned short* Wp    = (unsigned short*)(ws + 211200000LL);     //   1,523,712 B

    const int GB   = (NA + 63) / 64;   // 1563
    const int GB32 = (NA + 31) / 32;   // 3125
    dim3 b256(256);

    pack_weights<<<372, b256, 0, stream>>>(wi_w, wh0_w, wh1_w, wah0_w, wah_w, wo_w, Wp);
    bond_gather<<<(NA*16 + 255)/256, b256, 0, stream>>>(f_bonds, a2b, bsum);
    init_gemm<<<GB, b256, 0, stream>>>(f_atoms, Wp + 0, wi_b, msgb0);

    // depth loop: bf16 state ping-pongs (no f32 carry)
    depth_step<<<GB32, b256, 0, stream>>>(msgb0, bsum, a2a,
        Wp + 40960,            wh0_b,       wh_g,       wh_bt,       wh_a,
        Wp + 262144,           wh1_b,       msgb1);
    depth_step<<<GB32, b256, 0, stream>>>(msgb1, bsum, a2a,
        Wp + 40960 + 73728,    wh0_b + 256, wh_g + 256, wh_bt + 256, wh_a + 1,
        Wp + 262144 + 65536,   wh1_b + 256, msgb0);
    depth_step<<<GB32, b256, 0, stream>>>(msgb0, bsum, a2a,
        Wp + 40960 + 147456,   wh0_b + 512, wh_g + 512, wh_bt + 512, wh_a + 2,
        Wp + 262144 + 131072,  wh1_b + 512, msgb1);

    tail_kernel<<<GB, b256, 0, stream>>>(f_atoms, msgb1, a2a, Wp,
        wah0_b, wah0_g, wah0_bt, wah0_a,
        wah_b, wah_g, wah_bt, wah_a,
        tune_g, tune_b, tune_a,
        wo_b, wo_g, wo_bt, wo_a,
        (float*)d_out);
}